// Round 7
// baseline (428.246 us; speedup 1.0000x reference)
//
#include <hip/hip_runtime.h>
#include <hip/hip_bf16.h>

#define B_ROWS 8192
#define D_DIM  2048
#define C_DIM  1000
#define C_PAD  1024

#define EPS32   1.1920928955078125e-07f
// GAMMA = 1/exp(100) ~ 3.7e-44. GAMMA*rex ~ 1e-40 << ulp(h3~6.9) ~ 4.8e-7,
// so loss == mean(h3) exactly in fp32. rex pipeline deleted (round 5).
// Round 7: two-dispatch structure — per-dispatch fixed cost (~50 us) dominates,
// so fuse_z and prep are folded into the GEMM's staging (fp32->bf16 in-register).

typedef __attribute__((ext_vector_type(8))) short short8;   // 8 bf16 = 4 VGPRs
typedef __attribute__((ext_vector_type(4))) float f32x4;    // MFMA accumulator

__device__ inline unsigned short f2bf(float x) {
  union { __hip_bfloat16 b; unsigned short u; } cv;
  cv.b = __float2bfloat16(x);
  return cv.u;
}

__device__ inline float wave_red(float v) {
#pragma unroll
  for (int off = 32; off > 0; off >>= 1) v += __shfl_down(v, off, 64);
  return v;
}

// ---- K1: probs_raw = bf16(feature+eps) @ bf16(cls_w)^T + cls_b
// 128x128 tile, BK=64, 4 waves x (4x4) 16x16x32 MFMA.
// A-staging: load feature+eps fp32, add, cvt to bf16, ds_write_b128 (fuse_z fused).
// B-staging: load cls_w fp32, cvt to bf16, ds_write_b128 (prep fused; rows>=1000 zero).
// LDS XOR swizzle kept: 16B chunk (row, cc) at slot row*8 + (cc ^ (row&7)).
// Grid (n=8 fastest, m=64): the 8 siblings sharing an A-strip run concurrently -> L3 reuse.
// Block (0,0) thread 0 zeroes the K2 completion counter (d_ws is poisoned each launch).
__global__ __launch_bounds__(256, 2) void gemm_fused(const float* __restrict__ feature,
                                                     const float* __restrict__ eps,
                                                     const float* __restrict__ cls_w,
                                                     const float* __restrict__ cls_b,
                                                     float* __restrict__ out,
                                                     unsigned int* __restrict__ counter) {
  __shared__ __align__(16) __hip_bfloat16 sA[128 * 64];
  __shared__ __align__(16) __hip_bfloat16 sB[128 * 64];
  const int tid = threadIdx.x;
  const int n0 = blockIdx.x * 128;
  const int m0 = blockIdx.y * 128;
  if (blockIdx.x == 0 && blockIdx.y == 0 && tid == 0) *counter = 0;
  const int w = tid >> 6, lane = tid & 63;
  const int wm = (w & 1) * 64, wn = (w >> 1) * 64;
  const int l15 = lane & 15, quad = lane >> 4;

  f32x4 acc[4][4] = {};

  for (int k0 = 0; k0 < D_DIM; k0 += 64) {
#pragma unroll
    for (int i = 0; i < 4; ++i) {           // A: 1024 16B-chunks (row, cc)
      int j = i * 256 + tid;
      int row = j >> 3, cc = j & 7;
      const float4* fp = (const float4*)(feature + (size_t)(m0 + row) * D_DIM + k0 + cc * 8);
      const float4* ep = (const float4*)(eps + (size_t)(m0 + row) * D_DIM + k0 + cc * 8);
      float4 f0 = fp[0], f1 = fp[1];
      float4 e0 = ep[0], e1 = ep[1];
      union { unsigned short u[8]; uint4 v; } pk;
      pk.u[0] = f2bf(f0.x + e0.x); pk.u[1] = f2bf(f0.y + e0.y);
      pk.u[2] = f2bf(f0.z + e0.z); pk.u[3] = f2bf(f0.w + e0.w);
      pk.u[4] = f2bf(f1.x + e1.x); pk.u[5] = f2bf(f1.y + e1.y);
      pk.u[6] = f2bf(f1.z + e1.z); pk.u[7] = f2bf(f1.w + e1.w);
      *(uint4*)&sA[(row * 8 + (cc ^ (row & 7))) * 8] = pk.v;
    }
#pragma unroll
    for (int i = 0; i < 4; ++i) {           // B: 1024 16B-chunks from cls_w fp32
      int j = i * 256 + tid;
      int row = j >> 3, cc = j & 7;
      int gr = n0 + row;
      union { unsigned short u[8]; uint4 v; } pk;
      if (gr < C_DIM) {
        const float4* bp = (const float4*)(cls_w + (size_t)gr * D_DIM + k0 + cc * 8);
        float4 b0 = bp[0], b1 = bp[1];
        pk.u[0] = f2bf(b0.x); pk.u[1] = f2bf(b0.y); pk.u[2] = f2bf(b0.z); pk.u[3] = f2bf(b0.w);
        pk.u[4] = f2bf(b1.x); pk.u[5] = f2bf(b1.y); pk.u[6] = f2bf(b1.z); pk.u[7] = f2bf(b1.w);
      } else {
        pk.v = make_uint4(0, 0, 0, 0);
      }
      *(uint4*)&sB[(row * 8 + (cc ^ (row & 7))) * 8] = pk.v;
    }
    __syncthreads();
#pragma unroll
    for (int kk = 0; kk < 64; kk += 32) {
      const int ccr = (kk >> 3) + quad;     // which 8-elem chunk along K
      short8 af[4], bfr[4];
#pragma unroll
      for (int i = 0; i < 4; ++i) {
        int r = wm + i * 16 + l15;
        af[i] = *(const short8*)&sA[(r * 8 + (ccr ^ (r & 7))) * 8];
      }
#pragma unroll
      for (int jn = 0; jn < 4; ++jn) {
        int r = wn + jn * 16 + l15;
        bfr[jn] = *(const short8*)&sB[(r * 8 + (ccr ^ (r & 7))) * 8];
      }
#pragma unroll
      for (int i = 0; i < 4; ++i)
#pragma unroll
        for (int jn = 0; jn < 4; ++jn)
          acc[i][jn] = __builtin_amdgcn_mfma_f32_16x16x32_bf16(af[i], bfr[jn], acc[i][jn], 0, 0, 0);
    }
    __syncthreads();
  }

  // epilogue: C/D layout col=lane&15, row=quad*4+reg  (m89-verified)
#pragma unroll
  for (int i = 0; i < 4; ++i) {
    int row = m0 + wm + i * 16 + quad * 4;
#pragma unroll
    for (int jn = 0; jn < 4; ++jn) {
      int col = n0 + wn + jn * 16 + l15;
      if (col < C_DIM) {
        float bias = cls_b[col];
#pragma unroll
        for (int r = 0; r < 4; ++r)
          out[(size_t)(row + r) * C_DIM + col] = acc[i][jn][r] + bias;
      }
    }
  }
}

// ---- K2: wave-autonomous per-row normalize+clamp+log + grid-wide loss reduction.
// One wave per row (4 rows/block). Per-block partial h3 sum -> global partial,
// device-scope counter; last block cooperatively reduces 2048 partials.
__global__ __launch_bounds__(256) void rownorm_final(float* __restrict__ out,
                                                     const int* __restrict__ target,
                                                     float* __restrict__ partial,
                                                     unsigned int* __restrict__ counter,
                                                     float* __restrict__ out_loss) {
  int bid = blockIdx.x;
  int b = bid * 4 + (threadIdx.x >> 6);
  int lane = threadIdx.x & 63;
  float* row = out + (size_t)b * C_DIM;

  float v[16];
  float s = 0.f;
#pragma unroll
  for (int k = 0; k < 4; ++k) {
    int c = k * 256 + lane * 4;
    if (c + 3 < C_DIM) {
      float4 f = *(const float4*)(row + c);
      v[k * 4 + 0] = f.x; v[k * 4 + 1] = f.y; v[k * 4 + 2] = f.z; v[k * 4 + 3] = f.w;
    } else {
#pragma unroll
      for (int i = 0; i < 4; ++i) v[k * 4 + i] = (c + i < C_DIM) ? row[c + i] : 0.f;
    }
    s += v[k * 4 + 0] + v[k * 4 + 1] + v[k * 4 + 2] + v[k * 4 + 3];
  }
  s = wave_red(s);
  float inv = 1.0f / __shfl(s, 0, 64);
  int t = target[b];

  float h3c = 0.f;   // this lane's contribution to -log p[target]
#pragma unroll
  for (int k = 0; k < 4; ++k) {
    int c = k * 256 + lane * 4;
    float lg[4];
#pragma unroll
    for (int i = 0; i < 4; ++i) {
      float p = v[k * 4 + i] * inv;
      p = fminf(fmaxf(p, EPS32), 1.0f - EPS32);
      lg[i] = __logf(p);
      if (c + i == t) h3c = -lg[i];
    }
    if (c + 3 < C_DIM) {
      *(float4*)(row + c) = make_float4(lg[0], lg[1], lg[2], lg[3]);
    } else {
#pragma unroll
      for (int i = 0; i < 4; ++i) if (c + i < C_DIM) row[c + i] = lg[i];
    }
  }

  // block partial: sum h3 over the 4 rows
  float h3 = wave_red(h3c);
  __shared__ float wsum[4];
  __shared__ bool is_last;
  int w = threadIdx.x >> 6;
  if (lane == 0) wsum[w] = h3;
  __syncthreads();
  if (threadIdx.x == 0) {
    partial[bid] = wsum[0] + wsum[1] + wsum[2] + wsum[3];
    __threadfence();
    unsigned int ticket = atomicAdd(counter, 1u);
    is_last = (ticket == gridDim.x - 1);
  }
  __syncthreads();
  if (is_last) {
    __threadfence();
    float s2 = 0.f;
#pragma unroll
    for (int k = 0; k < 8; ++k) s2 += partial[threadIdx.x + k * 256];
    s2 = wave_red(s2);
    if (lane == 0) wsum[w] = s2;
    __syncthreads();
    if (threadIdx.x == 0)
      out_loss[0] = (wsum[0] + wsum[1] + wsum[2] + wsum[3]) * (1.0f / B_ROWS);
  }
}

extern "C" void kernel_launch(void* const* d_in, const int* in_sizes, int n_in,
                              void* d_out, int out_size, void* d_ws, size_t ws_size,
                              hipStream_t stream) {
  const float* feature = (const float*)d_in[0];
  const float* cls_w   = (const float*)d_in[3];
  const float* cls_b   = (const float*)d_in[4];
  const float* eps     = (const float*)d_in[5];
  const int*   target  = (const int*)d_in[6];
  float* out = (float*)d_out;
  float* out_loss = out + (size_t)B_ROWS * C_DIM;

  char* ws = (char*)d_ws;
  float*        partial = (float*)ws;                    // 2048 * 4 = 8192 B
  unsigned int* counter = (unsigned int*)(ws + 8192);    // 4 B

  gemm_fused<<<dim3(C_PAD / 128, B_ROWS / 128), 256, 0, stream>>>(feature, eps, cls_w, cls_b,
                                                                  out, counter);
  rownorm_final<<<dim3(B_ROWS / 4), 256, 0, stream>>>(out, target, partial, counter, out_loss);
}

// Round 8
// 338.132 us; speedup vs baseline: 1.2665x; 1.2665x over previous
//
#include <hip/hip_runtime.h>
#include <hip/hip_bf16.h>

#define B_ROWS 8192
#define D_DIM  2048
#define C_DIM  1000
#define C_PAD  1024

#define EPS32   1.1920928955078125e-07f
// GAMMA = 1/exp(100) ~ 3.7e-44: GAMMA*rex is sub-ulp vs h3 ~ 6.9 -> loss = mean(h3).
// R7 lesson: do NOT fuse the fp32->bf16 A-conversion into the GEMM (4x A traffic,
// FETCH 528 MB). Precompute z_bf once; the GEMM's 8x N-re-read is L3-absorbed.
// R8: two dispatches — K1 (z_bf + clsw cast + counter init), K2 (GEMM + per-strip
// fused rownorm/loss via 8-sibling completion counters; no grid barrier).

typedef __attribute__((ext_vector_type(8))) short short8;   // 8 bf16 = 4 VGPRs
typedef __attribute__((ext_vector_type(4))) float f32x4;    // MFMA accumulator

#define GLOAD_LDS16(gptr, lptr) \
  __builtin_amdgcn_global_load_lds((const __attribute__((address_space(1))) void*)(gptr), \
                                   (__attribute__((address_space(3))) void*)(lptr), 16, 0, 0)

__device__ inline unsigned short f2bf(float x) {
  union { __hip_bfloat16 b; unsigned short u; } cv;
  cv.b = __float2bfloat16(x);
  return cv.u;
}

__device__ inline float wave_red(float v) {
#pragma unroll
  for (int off = 32; off > 0; off >>= 1) v += __shfl_down(v, off, 64);
  return v;
}

// ---- K1:
//   blocks [0,16384):      z_bf[i] = bf16(feature[i] + eps[i]), one float4-pair/thread.
//   blocks [16384,17408):  cast cls_w [1000,2048] -> bf16 padded [1024,2048];
//                          block 16384 also zeroes the K2 counters (ws is 0xAA-poisoned).
__global__ __launch_bounds__(256) void fuse_z(const float4* __restrict__ f4,
                                              const float4* __restrict__ e4,
                                              uint2* __restrict__ z,
                                              const float* __restrict__ cls_w,
                                              __hip_bfloat16* __restrict__ clsw_bf,
                                              unsigned int* __restrict__ strip_cnt) {
  int bid = blockIdx.x;
  if (bid < 16384) {
    int i = bid * 256 + threadIdx.x;
    float4 f = f4[i];
    float4 e = e4[i];
    union { unsigned short u[4]; uint2 v; } pz;
    pz.u[0] = f2bf(f.x + e.x);
    pz.u[1] = f2bf(f.y + e.y);
    pz.u[2] = f2bf(f.z + e.z);
    pz.u[3] = f2bf(f.w + e.w);
    z[i] = pz.v;
  } else {
    if (bid == 16384 && threadIdx.x < 66) strip_cnt[threadIdx.x] = 0;  // 64 strips + counter2 + pad
    int j = ((bid - 16384) * 256 + threadIdx.x) * 8;   // elem idx in [1024][2048]
    int row = j >> 11;
    int col = j & 2047;
    union { unsigned short u[8]; uint4 v; } pk;
    if (row < C_DIM) {
      const float* src = cls_w + (size_t)row * D_DIM + col;
#pragma unroll
      for (int i2 = 0; i2 < 8; ++i2) pk.u[i2] = f2bf(src[i2]);
    } else {
#pragma unroll
      for (int i2 = 0; i2 < 8; ++i2) pk.u[i2] = 0;
    }
    *(uint4*)((unsigned short*)clsw_bf + j) = pk.v;
  }
}

// ---- K2: probs_raw = z @ cls_w^T + cls_b, then per-m-strip fused normalize+log+loss.
// GEMM: 128x128 tile, BK=64, 4 waves x (4x4) 16x16x32 MFMA, XOR-swizzled LDS,
// global_load_lds width-16 staging (identical to R6's gemm_bt).
// Strip logic: grid (m=64, n=8). After epilogue: release-fence + atomicAdd on
// strip_cnt[m]; the 8th arriver (all 8 siblings' stores now device-visible)
// normalizes rows [m0, m0+128) — reads are L2/L3-hot — and accumulates strip h3.
// The 64th strip-finisher sums strip_h3[64] and writes the scalar loss.
__global__ __launch_bounds__(256) void gemm_fused(const __hip_bfloat16* __restrict__ A,
                                                  const __hip_bfloat16* __restrict__ Bt,
                                                  const float* __restrict__ cls_b,
                                                  const int* __restrict__ target,
                                                  float* __restrict__ out,
                                                  unsigned int* __restrict__ strip_cnt,
                                                  float* __restrict__ strip_h3,
                                                  float* __restrict__ out_loss) {
  __shared__ __align__(16) __hip_bfloat16 sA[128 * 64];
  __shared__ __align__(16) __hip_bfloat16 sB[128 * 64];
  const int tid = threadIdx.x;
  const int m0 = blockIdx.x * 128;
  const int n0 = blockIdx.y * 128;
  const int w = tid >> 6, lane = tid & 63;
  const int wm = (w & 1) * 64, wn = (w >> 1) * 64;
  const int l15 = lane & 15, quad = lane >> 4;

  f32x4 acc[4][4] = {};

  for (int k0 = 0; k0 < D_DIM; k0 += 64) {
#pragma unroll
    for (int i = 0; i < 4; ++i) {
      int j = i * 256 + tid;          // LDS slot: 1024 chunks of 16B per 128x64 tile
      int row = j >> 3;
      int cc = (j & 7) ^ (row & 7);   // inverse of the swizzle (XOR is an involution)
      const __hip_bfloat16* srcA = A + (size_t)(m0 + row) * D_DIM + k0 + cc * 8;
      const __hip_bfloat16* srcB = Bt + (size_t)(n0 + row) * D_DIM + k0 + cc * 8;
      GLOAD_LDS16(srcA, &sA[j * 8]);
      GLOAD_LDS16(srcB, &sB[j * 8]);
    }
    __syncthreads();
#pragma unroll
    for (int kk = 0; kk < 64; kk += 32) {
      const int ccr = (kk >> 3) + quad;   // which 8-elem chunk along K
      short8 af[4], bfr[4];
#pragma unroll
      for (int i = 0; i < 4; ++i) {
        int r = wm + i * 16 + l15;
        af[i] = *(const short8*)&sA[(r * 8 + (ccr ^ (r & 7))) * 8];
      }
#pragma unroll
      for (int jn = 0; jn < 4; ++jn) {
        int r = wn + jn * 16 + l15;
        bfr[jn] = *(const short8*)&sB[(r * 8 + (ccr ^ (r & 7))) * 8];
      }
#pragma unroll
      for (int i = 0; i < 4; ++i)
#pragma unroll
        for (int jn = 0; jn < 4; ++jn)
          acc[i][jn] = __builtin_amdgcn_mfma_f32_16x16x32_bf16(af[i], bfr[jn], acc[i][jn], 0, 0, 0);
    }
    __syncthreads();
  }

  // epilogue: C/D layout col=lane&15, row=quad*4+reg  (m89-verified)
#pragma unroll
  for (int i = 0; i < 4; ++i) {
    int row = m0 + wm + i * 16 + quad * 4;
#pragma unroll
    for (int jn = 0; jn < 4; ++jn) {
      int col = n0 + wn + jn * 16 + l15;
      if (col < C_DIM) {
        float bias = cls_b[col];
#pragma unroll
        for (int r = 0; r < 4; ++r)
          out[(size_t)(row + r) * C_DIM + col] = acc[i][jn][r] + bias;
      }
    }
  }

  // ---- per-strip completion: 8th sibling normalizes the strip ----
  __threadfence();                       // release: make our stores device-visible
  __shared__ unsigned int ticket_s;
  if (tid == 0) ticket_s = atomicAdd(&strip_cnt[blockIdx.x], 1u);
  __syncthreads();
  if (ticket_s != 7) return;             // block-uniform branch
  __threadfence();                       // acquire: see all 8 siblings' stores

  // 4 waves x 32 rows; wave-per-row: lane owns 16 cols as 4 float4 chunks.
  float h3w = 0.f;
  for (int rr = 0; rr < 32; ++rr) {
    int b = m0 + w * 32 + rr;
    float* row = out + (size_t)b * C_DIM;   // 1000 floats = 4000 B, 16B-aligned
    float v[16];
    float s = 0.f;
#pragma unroll
    for (int k = 0; k < 4; ++k) {
      int c = k * 256 + lane * 4;
      if (c + 3 < C_DIM) {
        float4 f = *(const float4*)(row + c);
        v[k * 4 + 0] = f.x; v[k * 4 + 1] = f.y; v[k * 4 + 2] = f.z; v[k * 4 + 3] = f.w;
      } else {
#pragma unroll
        for (int i = 0; i < 4; ++i) v[k * 4 + i] = (c + i < C_DIM) ? row[c + i] : 0.f;
      }
      s += v[k * 4 + 0] + v[k * 4 + 1] + v[k * 4 + 2] + v[k * 4 + 3];
    }
    s = wave_red(s);
    float inv = 1.0f / __shfl(s, 0, 64);
    int t = target[b];
#pragma unroll
    for (int k = 0; k < 4; ++k) {
      int c = k * 256 + lane * 4;
      float lg[4];
#pragma unroll
      for (int i = 0; i < 4; ++i) {
        float p = v[k * 4 + i] * inv;
        p = fminf(fmaxf(p, EPS32), 1.0f - EPS32);
        lg[i] = __logf(p);
        if (c + i == t) h3w += -lg[i];
      }
      if (c + 3 < C_DIM) {
        *(float4*)(row + c) = make_float4(lg[0], lg[1], lg[2], lg[3]);
      } else {
#pragma unroll
        for (int i = 0; i < 4; ++i) if (c + i < C_DIM) row[c + i] = lg[i];
      }
    }
  }

  // strip h3 total -> strip_h3[m]; 64th strip-finisher writes the loss
  h3w = wave_red(h3w);
  __shared__ float hsum[4];
  if (lane == 0) hsum[w] = h3w;
  __syncthreads();
  if (tid == 0) {
    strip_h3[blockIdx.x] = hsum[0] + hsum[1] + hsum[2] + hsum[3];
    __threadfence();
    unsigned int t2 = atomicAdd(&strip_cnt[64], 1u);   // counter2
    if (t2 == 63) {
      __threadfence();
      float s = 0.f;
      for (int i = 0; i < 64; ++i) s += strip_h3[i];
      out_loss[0] = s * (1.0f / B_ROWS);
    }
  }
}

extern "C" void kernel_launch(void* const* d_in, const int* in_sizes, int n_in,
                              void* d_out, int out_size, void* d_ws, size_t ws_size,
                              hipStream_t stream) {
  const float* feature = (const float*)d_in[0];
  const float* cls_w   = (const float*)d_in[3];
  const float* cls_b   = (const float*)d_in[4];
  const float* eps     = (const float*)d_in[5];
  const int*   target  = (const int*)d_in[6];
  float* out = (float*)d_out;
  float* out_loss = out + (size_t)B_ROWS * C_DIM;

  char* ws = (char*)d_ws;
  __hip_bfloat16* z_bf      = (__hip_bfloat16*)ws;                 // 33554432 B
  __hip_bfloat16* clsw_bf   = (__hip_bfloat16*)(ws + 33554432);    //  4194304 B
  unsigned int*   strip_cnt = (unsigned int*)(ws + 37748736);      // 66 * 4 B (64 strips + counter2 + pad)
  float*          strip_h3  = (float*)(ws + 37749248);             // 64 * 4 B

  fuse_z<<<dim3(16384 + 1024), 256, 0, stream>>>((const float4*)feature, (const float4*)eps,
                                                 (uint2*)z_bf, cls_w, clsw_bf, strip_cnt);
  gemm_fused<<<dim3(B_ROWS / 128, C_PAD / 128), 256, 0, stream>>>(z_bf, clsw_bf, cls_b, target,
                                                                  out, strip_cnt, strip_h3, out_loss);
}